// Round 5
// baseline (76.981 us; speedup 1.0000x reference)
//
#include <hip/hip_runtime.h>

#define PH 7
#define PW 7
#define SCALE 0.0625f

// Problem constants: feature_map (1,128,56,56) fp32, rois (64,5) fp32,
// out (64,128,7,7) fp32.
#define NB 64
#define NC 128
#define FH 56
#define FW 56
#define NPIX (FH * FW)   // 3136

// Kernel 1: transpose [C,H,W] -> [H,W,C] into d_ws. Writes fully coalesced;
// reads are a one-time 64-line gather per wave (L2-resident, latency hidden
// by 6272 independent waves).
__global__ __launch_bounds__(256) void transpose_chw_hwc(
    const float* __restrict__ feat, float* __restrict__ ws)
{
    int tid = blockIdx.x * 256 + threadIdx.x;   // 0 .. 401407
    int c   = tid & (NC - 1);
    int pix = tid >> 7;
    ws[tid] = feat[c * NPIX + pix];
}

// Kernel 2: one block per (bin, b), lanes = channels. All control flow is
// wave-uniform; with the [H,W,C] layout every cell load is 512 consecutive
// bytes across the 128 threads (2 cache lines per wave) -> fully coalesced.
__global__ __launch_bounds__(NC) void DualMaskRoIPool_kernel(
    const float* __restrict__ ws,      // [H,W,C]
    const float* __restrict__ rois1,   // [B,5]
    const float* __restrict__ rois2,   // [B,5]
    float* __restrict__ out)           // [B,C,PH,PW]
{
    const int c   = threadIdx.x;       // 0..127 (2 waves)
    const int bin = blockIdx.x;        // 0..48
    const int b   = blockIdx.y;        // 0..63
    const int i   = bin / PW;
    const int j   = bin % PW;

    // ----- scalar ROI decode (round-half-even, clamp upper bound only) -----
    const float* r1 = rois1 + b * 5;
    const float* r2 = rois2 + b * 5;
    int x1a = (int)rintf(r1[1] * SCALE);
    int y1a = (int)rintf(r1[2] * SCALE);
    int x2a = (int)rintf(r1[3] * SCALE);
    int y2a = (int)rintf(r1[4] * SCALE);
    int x1b = (int)rintf(r2[1] * SCALE);
    int y1b = (int)rintf(r2[2] * SCALE);
    int x2b = (int)rintf(r2[3] * SCALE);
    int y2b = (int)rintf(r2[4] * SCALE);
    if (x1a >= FW) x1a = FW - 1;
    if (y1a >= FH) y1a = FH - 1;
    if (x2a >= FW) x2a = FW - 1;
    if (y2a >= FH) y2a = FH - 1;
    if (x1b >= FW) x1b = FW - 1;
    if (y1b >= FH) y1b = FH - 1;
    if (x2b >= FW) x2b = FW - 1;
    if (y2b >= FH) y2b = FH - 1;

    // ----- union box -----
    const int ux1 = min(x1a, x1b);
    const int uy1 = min(y1a, y1b);
    const int ux2 = max(x2a, x2b);
    const int uy2 = max(y2a, y2b);
    const int h = uy2 - uy1 + 1;   // >= 1
    const int w = ux2 - ux1 + 1;   // >= 1

    // ----- adaptive bin bounds (abs coords, [start,end)); never empty -----
    const int rs = uy1 + (i * h) / PH;
    const int re = uy1 + ((i + 1) * h + PH - 1) / PH;
    const int cs = ux1 + (j * w) / PW;
    const int ce = ux1 + ((j + 1) * w + PW - 1) / PW;

    float m = -1e30f;
    bool has_zero = false;   // uniform: any in-bin cell outside both ROIs
    for (int y = rs; y < re; ++y) {
        const bool iny1 = (y >= y1a) && (y <= y2a);
        const bool iny2 = (y >= y1b) && (y <= y2b);
        if (!iny1 && !iny2) { has_zero = true; continue; }  // whole row zero
        const float* wrow = ws + (y * FW) * NC;
        for (int x = cs; x < ce; ++x) {
            const bool in = (iny1 && (x >= x1a) && (x <= x2a)) ||
                            (iny2 && (x >= x1b) && (x <= x2b));
            if (in) m = fmaxf(m, wrow[x * NC + c]);  // coalesced: c fastest
            else    has_zero = true;
        }
    }
    if (has_zero) m = fmaxf(m, 0.0f);   // masked-out cells contribute exactly 0

    out[((b * NC + c) * PH + i) * PW + j] = m;
}

extern "C" void kernel_launch(void* const* d_in, const int* in_sizes, int n_in,
                              void* d_out, int out_size, void* d_ws, size_t ws_size,
                              hipStream_t stream) {
    const float* feat  = (const float*)d_in[0];
    const float* rois1 = (const float*)d_in[1];
    const float* rois2 = (const float*)d_in[2];
    float* out = (float*)d_out;
    float* ws  = (float*)d_ws;          // 401408 floats = 1.6 MB scratch

    // 1) transpose feature map to channel-fastest layout
    transpose_chw_hwc<<<(NC * NPIX) / 256, 256, 0, stream>>>(feat, ws);
    // 2) pool (stream order guarantees the dependency)
    dim3 grid(PH * PW, NB);   // 49 x 64 blocks, one per (bin, roi)
    DualMaskRoIPool_kernel<<<grid, NC, 0, stream>>>(ws, rois1, rois2, out);
}

// Round 7
// 69.753 us; speedup vs baseline: 1.1036x; 1.1036x over previous
//
#include <hip/hip_runtime.h>

#define PH 7
#define PW 7
#define SCALE 0.0625f

// Problem constants (from setup_inputs): feature_map (1,128,56,56) fp32,
// rois_1/rois_2 (64,5) fp32, out (64,128,7,7) fp32.
#define NB 64
#define NC 128
#define FH 56
#define FW 56

// Best-measured design (dur_us 69.4): one thread per output element, ROI
// decode forced wave-uniform via readfirstlane (NC*PH*PW = 6272 is a
// multiple of 64, so b is constant across each wave). Single launch, no
// d_ws usage. Measured equal-or-better than wave-uniform-control-flow and
// transpose+coalesced variants -> timed region is harness-floor dominated.
__global__ __launch_bounds__(256) void DualMaskRoIPool_kernel(
    const float* __restrict__ feat,    // [C,H,W]
    const float* __restrict__ rois1,   // [B,5]
    const float* __restrict__ rois2,   // [B,5]
    float* __restrict__ out)           // [B,C,PH,PW]
{
    const int total = NB * NC * PH * PW;
    int tid = blockIdx.x * blockDim.x + threadIdx.x;
    if (tid >= total) return;

    int j = tid % PW;
    int i = (tid / PW) % PH;
    int c = (tid / (PW * PH)) % NC;
    int b = tid / (PW * PH * NC);
    // b is wave-uniform; make it provably so -> scalar ROI loads + uniform decode
    b = __builtin_amdgcn_readfirstlane(b);

    // ----- zoom both ROIs (round-half-even, clamp upper bound only) -----
    const float* r1 = rois1 + b * 5;
    const float* r2 = rois2 + b * 5;
    int x1a = (int)rintf(r1[1] * SCALE);
    int y1a = (int)rintf(r1[2] * SCALE);
    int x2a = (int)rintf(r1[3] * SCALE);
    int y2a = (int)rintf(r1[4] * SCALE);
    int x1b = (int)rintf(r2[1] * SCALE);
    int y1b = (int)rintf(r2[2] * SCALE);
    int x2b = (int)rintf(r2[3] * SCALE);
    int y2b = (int)rintf(r2[4] * SCALE);
    if (x1a >= FW) x1a = FW - 1;
    if (y1a >= FH) y1a = FH - 1;
    if (x2a >= FW) x2a = FW - 1;
    if (y2a >= FH) y2a = FH - 1;
    if (x1b >= FW) x1b = FW - 1;
    if (y1b >= FH) y1b = FH - 1;
    if (x2b >= FW) x2b = FW - 1;
    if (y2b >= FH) y2b = FH - 1;

    // ----- union box -----
    int ux1 = min(x1a, x1b);
    int uy1 = min(y1a, y1b);
    int ux2 = max(x2a, x2b);
    int uy2 = max(y2a, y2b);
    int h = uy2 - uy1 + 1;   // >= 1
    int w = ux2 - ux1 + 1;   // >= 1

    // ----- adaptive bin bounds (abs coords, [start,end)); never empty -----
    int rs = uy1 + (i * h) / PH;
    int re = uy1 + ((i + 1) * h + PH - 1) / PH;
    int cs = ux1 + (j * w) / PW;
    int ce = ux1 + ((j + 1) * w + PW - 1) / PW;

    const float* fc = feat + c * (FH * FW);
    float m = -1e30f;  // NEG init; bins never empty (h>=1 => re>rs)
    for (int y = rs; y < re; ++y) {
        bool iny1 = (y >= y1a) && (y <= y2a);
        bool iny2 = (y >= y1b) && (y <= y2b);
        const float* frow = fc + y * FW;
        for (int x = cs; x < ce; ++x) {
            bool in = (iny1 && (x >= x1a) && (x <= x2a)) ||
                      (iny2 && (x >= x1b) && (x <= x2b));
            float v = in ? frow[x] : 0.0f;   // dual-mask: 0 in union, outside both ROIs
            m = fmaxf(m, v);
        }
    }
    out[tid] = m;
}

extern "C" void kernel_launch(void* const* d_in, const int* in_sizes, int n_in,
                              void* d_out, int out_size, void* d_ws, size_t ws_size,
                              hipStream_t stream) {
    const float* feat  = (const float*)d_in[0];
    const float* rois1 = (const float*)d_in[1];
    const float* rois2 = (const float*)d_in[2];
    float* out = (float*)d_out;

    const int total = NB * NC * PH * PW;             // 401408
    const int block = 256;
    const int grid = (total + block - 1) / block;    // 1568
    DualMaskRoIPool_kernel<<<grid, block, 0, stream>>>(feat, rois1, rois2, out);
}